// Round 13
// baseline (305.957 us; speedup 1.0000x reference)
//
#include <hip/hip_runtime.h>
#include <math.h>

#define B 8
#define C 64
#define HW 96
#define NWV 36864            // per-variant weight elems: 9 taps * 64 co * 64 ci

typedef __attribute__((ext_vector_type(8)))  short short8;
typedef __attribute__((ext_vector_type(16))) float floatx16;

__device__ __forceinline__ unsigned short f2bf(float f) {
    unsigned int u = __float_as_uint(f);
    unsigned int r = (u + 0x7fffu + ((u >> 16) & 1u)) >> 16;
    return (unsigned short)r;
}

// tap rotation: effective kernel for rotation k is K'[i,j] = r^k(K)[i,j], r(K)[i,j]=K[2-j,i]
__device__ __forceinline__ void rotmap(int k, int ta, int tb, int& sa, int& sb) {
    switch (k) {
        case 0: sa = ta;     sb = tb;     break;
        case 1: sa = 2 - tb; sb = ta;     break;
        case 2: sa = 2 - ta; sb = 2 - tb; break;
        default: sa = tb;    sb = 2 - ta; break;
    }
}

// ---------------- fused prep: prep_w (blk 0..2303) + prep_x (2304..3071) +
// border_clear (3072..4671) + prep_bias (4672). (r12 version, verbatim)
__global__ __launch_bounds__(256) void prep_all(
    const float* __restrict__ dcn_w, const float* __restrict__ c2w,
    const float* __restrict__ c3w,
    const float* __restrict__ dcn_b, const float* __restrict__ c2b,
    const float* __restrict__ c3b,
    const float* __restrict__ gamma, const float* __restrict__ beta,
    const float* __restrict__ mean, const float* __restrict__ var_,
    const float* __restrict__ x,
    unsigned short* __restrict__ Wall, float* __restrict__ biasg,
    unsigned short* __restrict__ xhwc, unsigned short* __restrict__ buf1) {

    __shared__ float row[64 * 97];   // used only by the prep_x branch (24,832 B)
    int blk = blockIdx.x, t = threadIdx.x;

    if (blk < 2304) {
        // ---- prep_w ----
        int idx = blk * 256 + t;                 // 2304*256 == 16*NWV exactly
        int v = idx / NWV, rem = idx % NWV;
        int tap  = rem >> 12;
        int w12  = rem & 4095;
        int ks   = w12 >> 10;
        int cf   = (w12 >> 9) & 1;
        int lane = (w12 >> 3) & 63;
        int j    = w12 & 7;
        int co = cf * 32 + (lane & 31);
        int ci = ks * 16 + (lane >> 5) * 8 + j;
        int ta = tap / 3, tb = tap % 3;
        const float* src; int k, srcci, l;
        if (v < 8)       { k = v & 3;  srcci = (ci + 8 * v) & 63; src = dcn_w; l = 0; }
        else if (v < 12) { k = v - 8;  srcci = ci; src = c2w; l = 1; }
        else             { k = v - 12; srcci = ci; src = c3w; l = 2; }
        int sa, sb; rotmap(k, ta, tb, sa, sb);
        float s = gamma[l * 64 + co] * rsqrtf(var_[l * 64 + co] + 1e-5f);
        Wall[idx] = f2bf(src[((co * 64 + srcci) * 3 + sa) * 3 + sb] * s);
    } else if (blk < 3072) {
        // ---- prep_x: NCHW fp32 -> NHWC bf16 ----
        int by = blk - 2304;
        int b = by / 96, y = by % 96;
        for (int e = t; e < 6144; e += 256) {
            int c = e / 96, xx = e - c * 96;
            row[c * 97 + xx] = x[(((size_t)(b * 64 + c) * 96 + y) * 96) + xx];
        }
        __syncthreads();
        for (int e = t; e < 6144; e += 256) {
            int xx = e >> 6, c = e & 63;
            xhwc[(((size_t)(b * 96 + y) * 96 + xx) << 6) + c] = f2bf(row[c * 97 + xx]);
        }
    } else if (blk < 4672) {
        // ---- border_clear: zero 4-wide ring of even-branch 104x104 frames ----
        int l = blk - 3072;
        int bx = l % 50, idx = l / 50;           // bx 0..49, idx 0..31
        int br = (idx >> 3) * 2, b = idx & 7;
        int z = br * 8 + b;
        int i = bx * 32 + (t >> 3);              // 0..1599 border pixels
        int g = t & 7;
        int r, c;
        if (i < 416)      { r = i / 104;              c = i % 104; }
        else if (i < 832) { int j2 = i - 416; r = 100 + j2 / 104; c = j2 % 104; }
        else              { int j2 = i - 832; r = 4 + (j2 >> 3); int c8 = j2 & 7;
                            c = (c8 < 4) ? c8 : 92 + c8; }
        uint4 zero = make_uint4(0u, 0u, 0u, 0u);
        *(uint4*)(buf1 + (size_t)z * (104 * 104 * 64) + ((size_t)(r * 104 + c) << 6) + (g << 3)) = zero;
    } else {
        // ---- prep_bias ----
        if (t < 192) {
            int l = t >> 6, c = t & 63;
            const float* cb = (l == 0) ? dcn_b : ((l == 1) ? c2b : c3b);
            float s = gamma[l * 64 + c] * rsqrtf(var_[l * 64 + c] + 1e-5f);
            biasg[t] = cb[c] * s + beta[l * 64 + c] - mean[l * 64 + c] * s;
        }
    }
}

// ---------------- conv1: 16x32 tile, wave owns 4 rows -> 2x weight reuse per load ------
// Same proven r1 index patterns with 2wv->4wv, rr 0..5, 18-row staged tile.
// LDS 18x34x64 bf16 = 78,336B (2 blocks/CU); transpose epilogue reuses xt (needs 65,536B).
// Per-wave weight loads (72 x 16B) now serve 4 output rows -> weight L2 traffic ~halved.
__global__ __launch_bounds__(256, 2) void conv1_k(
    const unsigned short* __restrict__ xhwc, unsigned short* __restrict__ buf1,
    const unsigned short* __restrict__ Wall, const float* __restrict__ biasg) {

    __shared__ __align__(16) unsigned short xt[18 * 34 * 64];   // 78,336 B

    int z = blockIdx.z, br = z >> 3, b = z & 7, odd = br & 1;
    int fy0 = blockIdx.y * 16, fx0 = blockIdx.x * 32;
    int t = threadIdx.x, lane = t & 63, wv = t >> 6;
    int n = lane & 31, kq = lane >> 5;

    const unsigned short* xb = xhwc + ((size_t)b * 96 * 96 << 6);
    const short8* Ag = (const short8*)(Wall + (size_t)br * NWV);

    // stage x: tile rows fy0-5..fy0+12, cols fx0-5.., zero OOB, key = tilecol&7
    for (int e = t; e < 4896; e += 256) {
        int p = e >> 3, g = e & 7;
        int yy = p / 34, xx = p - yy * 34;
        int gy = fy0 - 5 + yy, gx = fx0 - 5 + xx;
        uint4 v = make_uint4(0u, 0u, 0u, 0u);
        if ((unsigned)gy < 96u && (unsigned)gx < 96u)
            v = *(const uint4*)(xb + ((size_t)(gy * 96 + gx) << 6) + (g << 3));
        *(uint4*)(xt + (p << 6) + ((g ^ (xx & 7)) << 3)) = v;
    }
    __syncthreads();

    floatx16 acc[2][4];   // [cf][pf], pf = 4 rows per wave
#pragma unroll
    for (int cf = 0; cf < 2; cf++)
#pragma unroll
        for (int pf = 0; pf < 4; pf++)
#pragma unroll
            for (int i = 0; i < 16; i++) acc[cf][pf][i] = 0.f;

#pragma unroll
    for (int ks = 0; ks < 4; ks++) {
#pragma unroll
        for (int tb = 0; tb < 3; tb++) {
            short8 a[3][2];
#pragma unroll
            for (int ta = 0; ta < 3; ta++)
#pragma unroll
                for (int cf = 0; cf < 2; cf++)
                    a[ta][cf] = Ag[(((ta * 3 + tb) * 4 + ks) * 2 + cf) * 64 + lane];
            int xx = n + tb;
            int g = ((ks * 2 + kq) ^ (xx & 7)) << 3;
            short8 bf[6];
#pragma unroll
            for (int rr = 0; rr < 6; rr++) {
                int p = (4 * wv + rr) * 34 + xx;
                bf[rr] = *(const short8*)(xt + (p << 6) + g);
            }
#pragma unroll
            for (int ta = 0; ta < 3; ta++)
#pragma unroll
                for (int pf = 0; pf < 4; pf++) {
                    int rr = pf + ta;
                    acc[0][pf] = __builtin_amdgcn_mfma_f32_32x32x16_bf16(a[ta][0], bf[rr], acc[0][pf], 0, 0, 0);
                    acc[1][pf] = __builtin_amdgcn_mfma_f32_32x32x16_bf16(a[ta][1], bf[rr], acc[1][pf], 0, 0, 0);
                }
        }
    }

    // bias (co0 = 4kq + 8rb + 32cf)
    float4 bv[2][4];
#pragma unroll
    for (int cf = 0; cf < 2; cf++)
#pragma unroll
        for (int rb = 0; rb < 4; rb++)
            bv[cf][rb] = *(const float4*)(biasg + 32 * cf + 8 * rb + 4 * kq);

    __syncthreads();   // xt reads done; reuse as transpose buffer (512 px * 128 B)
#pragma unroll
    for (int pf = 0; pf < 4; pf++) {
        int pq = (4 * wv + pf) * 32 + n;
        int key = (pq & 7) << 1;
#pragma unroll
        for (int cf = 0; cf < 2; cf++)
#pragma unroll
            for (int rb = 0; rb < 4; rb++) {
                int u = kq + 2 * rb + 8 * cf;
                float v0 = fmaxf(acc[cf][pf][rb * 4 + 0] + bv[cf][rb].x, 0.f);
                float v1 = fmaxf(acc[cf][pf][rb * 4 + 1] + bv[cf][rb].y, 0.f);
                float v2 = fmaxf(acc[cf][pf][rb * 4 + 2] + bv[cf][rb].z, 0.f);
                float v3 = fmaxf(acc[cf][pf][rb * 4 + 3] + bv[cf][rb].w, 0.f);
                uint2 pk = make_uint2((unsigned)f2bf(v0) | ((unsigned)f2bf(v1) << 16),
                                      (unsigned)f2bf(v2) | ((unsigned)f2bf(v3) << 16));
                *(uint2*)((char*)xt + pq * 128 + ((u ^ key) << 3)) = pk;
            }
    }
    __syncthreads();

    unsigned short* fb = buf1 + (size_t)z * (104 * 104 * 64);
    int lo = odd ? 0 : 4, hi = odd ? 104 : 100;
    for (int e = t; e < 4096; e += 256) {
        int px = e >> 3, g = e & 7;
        int key = (px & 7) << 1;
        uint4 v = *(const uint4*)((const char*)xt + px * 128 + (((2 * g) ^ key) << 3));
        int lr = px >> 5, nn = px & 31;
        int f = fy0 + lr, fc = fx0 + nn;
        if (f >= lo && f < hi && fc >= lo && fc < hi)
            *(uint4*)(fb + ((size_t)(f * 104 + fc) << 6) + (g << 3)) = v;
    }
}

// ---------------- fused conv2+conv3 -> maxbuf (r11/r12 version, verbatim: best measured) --
__global__ __launch_bounds__(512, 2) void conv23_k(
    const unsigned short* __restrict__ buf1, float* __restrict__ maxb,
    const unsigned short* __restrict__ Wall, const float* __restrict__ biasg) {

    __shared__ __align__(16) unsigned char ubuf[960 * 128];    // 122,880 B (union: xs | c2out)
    unsigned short* xs = (unsigned short*)ubuf;                // 24x40 px, 64 ci
    char* c2out = (char*)ubuf;                                 // 720 px * 128 B

    int z = blockIdx.z, br = z >> 3, odd = br & 1;
    int oy0 = blockIdx.y * 16, ox0 = blockIdx.x * 32;
    int t = threadIdx.x, lane = t & 63, wv = t >> 6;
    int n = lane & 31, kq = lane >> 5;

    const unsigned short* fb = buf1 + (size_t)z * (104 * 104 * 64);
    const short8* A2 = (const short8*)(Wall + (size_t)(8  + (br & 3)) * NWV);
    const short8* A3 = (const short8*)(Wall + (size_t)(12 + (br & 3)) * NWV);

    // ---- P1: stage xs FULL 64ci (24x40 px), 15 uint4/thread ----
    for (int e = t; e < 7680; e += 512) {
        int p = e >> 3, g = e & 7;
        int yy = p / 40, xx = p - yy * 40;
        uint4 v = *(const uint4*)(fb + ((size_t)((oy0 + yy) * 104 + ox0 + xx) << 6) + (g << 3));
        *(uint4*)(xs + (p << 6) + ((g ^ (xx & 7)) << 3)) = v;
    }

    // per-wave conv2-out pixel coords (3 chunks of 32, q-linear over 20x36, clamped)
    int q_[3], row2_[3], col2_[3];
#pragma unroll
    for (int jj = 0; jj < 3; jj++) {
        int q = 96 * wv + 32 * jj + n;
        q_[jj] = q;
        int qc = (q < 720) ? q : 719;
        int r2 = qc / 36;
        row2_[jj] = r2;
        col2_[jj] = qc - 36 * r2;
    }

    floatx16 acc2[3][2];   // [jj][cf]
#pragma unroll
    for (int jj = 0; jj < 3; jj++)
#pragma unroll
        for (int cf = 0; cf < 2; cf++)
#pragma unroll
            for (int i = 0; i < 16; i++) acc2[jj][cf][i] = 0.f;

    __syncthreads();   // xs staged

    // ---- conv2: single sweep over 4 ks quarters (full K resident in xs) ----
#pragma unroll
    for (int ks = 0; ks < 4; ks++) {
#pragma unroll
        for (int tb = 0; tb < 3; tb++) {
            short8 a[3][2];
#pragma unroll
            for (int ta = 0; ta < 3; ta++)
#pragma unroll
                for (int cf = 0; cf < 2; cf++)
                    a[ta][cf] = A2[(((ta * 3 + tb) * 4 + ks) * 2 + cf) * 64 + lane];
#pragma unroll
            for (int jj = 0; jj < 3; jj++) {
                int colx = col2_[jj] + 2 * tb;
                int gsw = ((ks * 2 + kq) ^ (colx & 7)) << 3;
#pragma unroll
                for (int ta = 0; ta < 3; ta++) {
                    int p = (row2_[jj] + 2 * ta) * 40 + colx;
                    short8 bfr = *(const short8*)(xs + (p << 6) + gsw);
                    acc2[jj][0] = __builtin_amdgcn_mfma_f32_32x32x16_bf16(a[ta][0], bfr, acc2[jj][0], 0, 0, 0);
                    acc2[jj][1] = __builtin_amdgcn_mfma_f32_32x32x16_bf16(a[ta][1], bfr, acc2[jj][1], 0, 0, 0);
                }
            }
        }
    }

    __syncthreads();   // xs reads complete before c2out (aliased) is written

    // ---- P3: conv2 epilogue -> c2out LDS (bias+relu, zero-mask even-parity borders) ----
    int rlo2 = (!odd && oy0 == 0)  ? 2  : 0;
    int rhi2 = (!odd && oy0 == 80) ? 18 : 20;
    int clo2 = (!odd && ox0 == 0)  ? 2  : 0;
    int chi2 = (!odd && ox0 == 64) ? 34 : 36;
    float4 bv2[2][4];
#pragma unroll
    for (int cf = 0; cf < 2; cf++)
#pragma unroll
        for (int rb = 0; rb < 4; rb++)
            bv2[cf][rb] = *(const float4*)(biasg + 64 + 32 * cf + 8 * rb + 4 * kq);

#pragma unroll
    for (int jj = 0; jj < 3; jj++) {
        if (q_[jj] < 720) {
            bool valid = (row2_[jj] >= rlo2) && (row2_[jj] < rhi2) &&
                         (col2_[jj] >= clo2) && (col2_[jj] < chi2);
            int key = col2_[jj] & 14;
#pragma unroll
            for (int cf = 0; cf < 2; cf++)
#pragma unroll
                for (int rb = 0; rb < 4; rb++) {
                    int u = kq + 2 * rb + 8 * cf;
                    float v0 = 0.f, v1 = 0.f, v2 = 0.f, v3 = 0.f;
                    if (valid) {
                        v0 = fmaxf(acc2[jj][cf][rb * 4 + 0] + bv2[cf][rb].x, 0.f);
                        v1 = fmaxf(acc2[jj][cf][rb * 4 + 1] + bv2[cf][rb].y, 0.f);
                        v2 = fmaxf(acc2[jj][cf][rb * 4 + 2] + bv2[cf][rb].z, 0.f);
                        v3 = fmaxf(acc2[jj][cf][rb * 4 + 3] + bv2[cf][rb].w, 0.f);
                    }
                    uint2 pk = make_uint2((unsigned)f2bf(v0) | ((unsigned)f2bf(v1) << 16),
                                          (unsigned)f2bf(v2) | ((unsigned)f2bf(v3) << 16));
                    *(uint2*)(c2out + q_[jj] * 128 + ((u ^ key) << 3)) = pk;
                }
        }
    }
    __syncthreads();

    // ---- P4: conv3 from c2out; wave owns out rows {2wv, 2wv+1} x 32 cols ----
    int r0 = 2 * wv;
    floatx16 acc3[2][2];   // [cf][pf]
#pragma unroll
    for (int cf = 0; cf < 2; cf++)
#pragma unroll
        for (int pf = 0; pf < 2; pf++)
#pragma unroll
            for (int i = 0; i < 16; i++) acc3[cf][pf][i] = 0.f;

#pragma unroll
    for (int ks = 0; ks < 4; ks++) {
#pragma unroll
        for (int tb = 0; tb < 3; tb++) {
            short8 a[3][2];
#pragma unroll
            for (int ta = 0; ta < 3; ta++)
#pragma unroll
                for (int cf = 0; cf < 2; cf++)
                    a[ta][cf] = A3[(((ta * 3 + tb) * 4 + ks) * 2 + cf) * 64 + lane];
            int col = n + 2 * tb;
            int key = col & 14;
            int ublk = 2 * (ks * 2 + kq);
            short8 bf[6];
#pragma unroll
            for (int rr = 0; rr < 6; rr++) {
                int q = (r0 + rr) * 36 + col;
                bf[rr] = *(const short8*)(c2out + q * 128 + ((ublk ^ key) << 3));
            }
#pragma unroll
            for (int ta = 0; ta < 3; ta++)
#pragma unroll
                for (int pf = 0; pf < 2; pf++) {
                    int rr = pf + 2 * ta;
                    acc3[0][pf] = __builtin_amdgcn_mfma_f32_32x32x16_bf16(a[ta][0], bf[rr], acc3[0][pf], 0, 0, 0);
                    acc3[1][pf] = __builtin_amdgcn_mfma_f32_32x32x16_bf16(a[ta][1], bf[rr], acc3[1][pf], 0, 0, 0);
                }
        }
    }

    // epilogue: bias + relu + max over 64 co -> maxb
    float4 bv3[2][4];
#pragma unroll
    for (int cf = 0; cf < 2; cf++)
#pragma unroll
        for (int rb = 0; rb < 4; rb++)
            bv3[cf][rb] = *(const float4*)(biasg + 128 + 32 * cf + 8 * rb + 4 * kq);

#pragma unroll
    for (int pf = 0; pf < 2; pf++) {
        float m = 0.f;
#pragma unroll
        for (int cf = 0; cf < 2; cf++)
#pragma unroll
            for (int rb = 0; rb < 4; rb++) {
                m = fmaxf(m, acc3[cf][pf][rb * 4 + 0] + bv3[cf][rb].x);
                m = fmaxf(m, acc3[cf][pf][rb * 4 + 1] + bv3[cf][rb].y);
                m = fmaxf(m, acc3[cf][pf][rb * 4 + 2] + bv3[cf][rb].z);
                m = fmaxf(m, acc3[cf][pf][rb * 4 + 3] + bv3[cf][rb].w);
            }
        m = fmaxf(m, 0.f);
        m = fmaxf(m, __shfl_xor(m, 32, 64));
        if (lane < 32)
            maxb[((size_t)z * 96 + oy0 + r0 + pf) * 96 + ox0 + n] = m;
    }
}

__global__ void final_k(const float* __restrict__ maxb, float* __restrict__ out) {
    int i = blockIdx.x * 256 + threadIdx.x;
    if (i < B * HW * HW) {
        int b = i / 9216, yx = i - b * 9216;
        float m = 0.f;
#pragma unroll
        for (int br = 0; br < 8; br++)
            m = fmaxf(m, maxb[((size_t)(br * 8 + b)) * 9216 + yx]);
        float v = 1.f / (1.f + expf(-m));
        out[i] = fminf(fmaxf(v, 1e-4f), 1.f - 1e-4f);
    }
}

// ---------------- launch ----------------

extern "C" void kernel_launch(void* const* d_in, const int* in_sizes, int n_in,
                              void* d_out, int out_size, void* d_ws, size_t ws_size,
                              hipStream_t stream) {
    const float* x     = (const float*)d_in[0];
    const float* dcn_w = (const float*)d_in[2];
    const float* dcn_b = (const float*)d_in[3];
    const float* c2w   = (const float*)d_in[4];
    const float* c2b   = (const float*)d_in[5];
    const float* c3w   = (const float*)d_in[6];
    const float* c3b   = (const float*)d_in[7];
    const float* gamma = (const float*)d_in[8];
    const float* beta  = (const float*)d_in[9];
    const float* mean  = (const float*)d_in[10];
    const float* var_  = (const float*)d_in[11];

    char* ws = (char*)d_ws;
    unsigned short* Wall = (unsigned short*)ws;                       // 1.18 MB
    size_t off = (size_t)16 * NWV * 2;
    float* biasg = (float*)(ws + off);            off += 1024;
    float* maxb  = (float*)(ws + off);            off += (size_t)64 * 9216 * 4;        // 2.36 MB
    unsigned short* xhwc = (unsigned short*)(ws + off); off += (size_t)B * 9216 * 64 * 2;    // 9.4 MB
    unsigned short* buf1 = (unsigned short*)(ws + off);                                 // 88.6 MB framed

    prep_all<<<4673, 256, 0, stream>>>(dcn_w, c2w, c3w, dcn_b, c2b, c3b,
                                       gamma, beta, mean, var_, x,
                                       Wall, biasg, xhwc, buf1);

    dim3 g1(4, 7, 64);
    conv1_k<<<g1, 256, 0, stream>>>(xhwc, buf1, Wall, biasg);

    dim3 g23(3, 6, 64);
    conv23_k<<<g23, 512, 0, stream>>>(buf1, maxb, Wall, biasg);

    final_k<<<(B * HW * HW + 255) / 256, 256, 0, stream>>>(maxb, (float*)d_out);
}

// Round 14
// 297.538 us; speedup vs baseline: 1.0283x; 1.0283x over previous
//
#include <hip/hip_runtime.h>
#include <math.h>

#define B 8
#define C 64
#define HW 96
#define NWV 36864            // per-variant weight elems: 9 taps * 64 co * 64 ci

typedef __attribute__((ext_vector_type(8)))  short short8;
typedef __attribute__((ext_vector_type(16))) float floatx16;

__device__ __forceinline__ unsigned short f2bf(float f) {
    unsigned int u = __float_as_uint(f);
    unsigned int r = (u + 0x7fffu + ((u >> 16) & 1u)) >> 16;
    return (unsigned short)r;
}

// tap rotation: effective kernel for rotation k is K'[i,j] = r^k(K)[i,j], r(K)[i,j]=K[2-j,i]
__device__ __forceinline__ void rotmap(int k, int ta, int tb, int& sa, int& sb) {
    switch (k) {
        case 0: sa = ta;     sb = tb;     break;
        case 1: sa = 2 - tb; sb = ta;     break;
        case 2: sa = 2 - ta; sb = 2 - tb; break;
        default: sa = tb;    sb = 2 - ta; break;
    }
}

// ---------------- fused prep: prep_w (blk 0..2303) + prep_x (2304..3071) +
// border_clear (3072..4671) + prep_bias (4672). All four are independent
// (disjoint outputs); branch is blockIdx-uniform so the prep_x barrier is safe.
__global__ __launch_bounds__(256) void prep_all(
    const float* __restrict__ dcn_w, const float* __restrict__ c2w,
    const float* __restrict__ c3w,
    const float* __restrict__ dcn_b, const float* __restrict__ c2b,
    const float* __restrict__ c3b,
    const float* __restrict__ gamma, const float* __restrict__ beta,
    const float* __restrict__ mean, const float* __restrict__ var_,
    const float* __restrict__ x,
    unsigned short* __restrict__ Wall, float* __restrict__ biasg,
    unsigned short* __restrict__ xhwc, unsigned short* __restrict__ buf1) {

    __shared__ float row[64 * 97];   // used only by the prep_x branch (24,832 B)
    int blk = blockIdx.x, t = threadIdx.x;

    if (blk < 2304) {
        // ---- prep_w ----
        int idx = blk * 256 + t;                 // 2304*256 == 16*NWV exactly
        int v = idx / NWV, rem = idx % NWV;
        int tap  = rem >> 12;
        int w12  = rem & 4095;
        int ks   = w12 >> 10;
        int cf   = (w12 >> 9) & 1;
        int lane = (w12 >> 3) & 63;
        int j    = w12 & 7;
        int co = cf * 32 + (lane & 31);
        int ci = ks * 16 + (lane >> 5) * 8 + j;
        int ta = tap / 3, tb = tap % 3;
        const float* src; int k, srcci, l;
        if (v < 8)       { k = v & 3;  srcci = (ci + 8 * v) & 63; src = dcn_w; l = 0; }
        else if (v < 12) { k = v - 8;  srcci = ci; src = c2w; l = 1; }
        else             { k = v - 12; srcci = ci; src = c3w; l = 2; }
        int sa, sb; rotmap(k, ta, tb, sa, sb);
        float s = gamma[l * 64 + co] * rsqrtf(var_[l * 64 + co] + 1e-5f);
        Wall[idx] = f2bf(src[((co * 64 + srcci) * 3 + sa) * 3 + sb] * s);
    } else if (blk < 3072) {
        // ---- prep_x: NCHW fp32 -> NHWC bf16 ----
        int by = blk - 2304;
        int b = by / 96, y = by % 96;
        for (int e = t; e < 6144; e += 256) {
            int c = e / 96, xx = e - c * 96;
            row[c * 97 + xx] = x[(((size_t)(b * 64 + c) * 96 + y) * 96) + xx];
        }
        __syncthreads();
        for (int e = t; e < 6144; e += 256) {
            int xx = e >> 6, c = e & 63;
            xhwc[(((size_t)(b * 96 + y) * 96 + xx) << 6) + c] = f2bf(row[c * 97 + xx]);
        }
    } else if (blk < 4672) {
        // ---- border_clear: zero 4-wide ring of even-branch 104x104 frames ----
        int l = blk - 3072;
        int bx = l % 50, idx = l / 50;           // bx 0..49, idx 0..31
        int br = (idx >> 3) * 2, b = idx & 7;
        int z = br * 8 + b;
        int i = bx * 32 + (t >> 3);              // 0..1599 border pixels
        int g = t & 7;
        int r, c;
        if (i < 416)      { r = i / 104;              c = i % 104; }
        else if (i < 832) { int j2 = i - 416; r = 100 + j2 / 104; c = j2 % 104; }
        else              { int j2 = i - 832; r = 4 + (j2 >> 3); int c8 = j2 & 7;
                            c = (c8 < 4) ? c8 : 92 + c8; }
        uint4 zero = make_uint4(0u, 0u, 0u, 0u);
        *(uint4*)(buf1 + (size_t)z * (104 * 104 * 64) + ((size_t)(r * 104 + c) << 6) + (g << 3)) = zero;
    } else {
        // ---- prep_bias ----
        if (t < 192) {
            int l = t >> 6, c = t & 63;
            const float* cb = (l == 0) ? dcn_b : ((l == 1) ? c2b : c3b);
            float s = gamma[l * 64 + c] * rsqrtf(var_[l * 64 + c] + 1e-5f);
            biasg[t] = cb[c] * s + beta[l * 64 + c] - mean[l * 64 + c] * s;
        }
    }
}

// ---------------- conv1 (r1 version): 1 branch/block -> framed buf1 (104x104, NHWC bf16) ----
__global__ __launch_bounds__(256, 2) void conv1_k(
    const unsigned short* __restrict__ xhwc, unsigned short* __restrict__ buf1,
    const unsigned short* __restrict__ Wall, const float* __restrict__ biasg) {

    __shared__ __align__(16) unsigned short xt[10 * 34 * 64];   // 43,520 B

    int z = blockIdx.z, br = z >> 3, b = z & 7, odd = br & 1;
    int fy0 = blockIdx.y * 8, fx0 = blockIdx.x * 32;
    int t = threadIdx.x, lane = t & 63, wv = t >> 6;
    int n = lane & 31, kq = lane >> 5;

    const unsigned short* xb = xhwc + ((size_t)b * 96 * 96 << 6);
    const short8* Ag = (const short8*)(Wall + (size_t)br * NWV);

    // stage x: tile rows fy0-5.. cols fx0-5.., zero OOB, key = tilecol&7
    for (int e = t; e < 2720; e += 256) {
        int p = e >> 3, g = e & 7;
        int yy = p / 34, xx = p - yy * 34;
        int gy = fy0 - 5 + yy, gx = fx0 - 5 + xx;
        uint4 v = make_uint4(0u, 0u, 0u, 0u);
        if ((unsigned)gy < 96u && (unsigned)gx < 96u)
            v = *(const uint4*)(xb + ((size_t)(gy * 96 + gx) << 6) + (g << 3));
        *(uint4*)(xt + (p << 6) + ((g ^ (xx & 7)) << 3)) = v;
    }
    __syncthreads();

    floatx16 acc[2][2];   // [cf][pf]
#pragma unroll
    for (int cf = 0; cf < 2; cf++)
#pragma unroll
        for (int pf = 0; pf < 2; pf++)
#pragma unroll
            for (int i = 0; i < 16; i++) acc[cf][pf][i] = 0.f;

#pragma unroll
    for (int ks = 0; ks < 4; ks++) {
#pragma unroll
        for (int tb = 0; tb < 3; tb++) {
            short8 a[3][2];
#pragma unroll
            for (int ta = 0; ta < 3; ta++)
#pragma unroll
                for (int cf = 0; cf < 2; cf++)
                    a[ta][cf] = Ag[(((ta * 3 + tb) * 4 + ks) * 2 + cf) * 64 + lane];
            int xx = n + tb;
            int g = ((ks * 2 + kq) ^ (xx & 7)) << 3;
            short8 bf[4];
#pragma unroll
            for (int rr = 0; rr < 4; rr++) {
                int p = (2 * wv + rr) * 34 + xx;
                bf[rr] = *(const short8*)(xt + (p << 6) + g);
            }
#pragma unroll
            for (int ta = 0; ta < 3; ta++)
#pragma unroll
                for (int pf = 0; pf < 2; pf++) {
                    int rr = pf + ta;
                    acc[0][pf] = __builtin_amdgcn_mfma_f32_32x32x16_bf16(a[ta][0], bf[rr], acc[0][pf], 0, 0, 0);
                    acc[1][pf] = __builtin_amdgcn_mfma_f32_32x32x16_bf16(a[ta][1], bf[rr], acc[1][pf], 0, 0, 0);
                }
        }
    }

    // bias (co0 = 4kq + 8rb + 32cf)
    float4 bv[2][4];
#pragma unroll
    for (int cf = 0; cf < 2; cf++)
#pragma unroll
        for (int rb = 0; rb < 4; rb++)
            bv[cf][rb] = *(const float4*)(biasg + 32 * cf + 8 * rb + 4 * kq);

    __syncthreads();   // xt reads done; reuse as transpose buffer (256 px * 128 B)
#pragma unroll
    for (int pf = 0; pf < 2; pf++) {
        int pq = (2 * wv + pf) * 32 + n;
        int key = (pq & 7) << 1;
#pragma unroll
        for (int cf = 0; cf < 2; cf++)
#pragma unroll
            for (int rb = 0; rb < 4; rb++) {
                int u = kq + 2 * rb + 8 * cf;
                float v0 = fmaxf(acc[cf][pf][rb * 4 + 0] + bv[cf][rb].x, 0.f);
                float v1 = fmaxf(acc[cf][pf][rb * 4 + 1] + bv[cf][rb].y, 0.f);
                float v2 = fmaxf(acc[cf][pf][rb * 4 + 2] + bv[cf][rb].z, 0.f);
                float v3 = fmaxf(acc[cf][pf][rb * 4 + 3] + bv[cf][rb].w, 0.f);
                uint2 pk = make_uint2((unsigned)f2bf(v0) | ((unsigned)f2bf(v1) << 16),
                                      (unsigned)f2bf(v2) | ((unsigned)f2bf(v3) << 16));
                *(uint2*)((char*)xt + pq * 128 + ((u ^ key) << 3)) = pk;
            }
    }
    __syncthreads();

    unsigned short* fb = buf1 + (size_t)z * (104 * 104 * 64);
    int lo = odd ? 0 : 4, hi = odd ? 104 : 100;
    for (int e = t; e < 2048; e += 256) {
        int px = e >> 3, g = e & 7;
        int key = (px & 7) << 1;
        uint4 v = *(const uint4*)((const char*)xt + px * 128 + (((2 * g) ^ key) << 3));
        int lr = px >> 5, nn = px & 31;
        int f = fy0 + lr, fc = fx0 + nn;
        if (f >= lo && f < hi && fc >= lo && fc < hi)
            *(uint4*)(fb + ((size_t)(f * 104 + fc) << 6) + (g << 3)) = v;
    }
}

// ---------------- fused conv2+conv3 -> maxbuf (r11/r12 version, verbatim: best measured) --
// Block: 512 thr (8 waves), 16x32 out tile. xs staged ONCE at full 64ci (122,880B);
// 3 barriers; c2out (720px x 128B) aliases xs after conv2 (guard barrier). Weights from
// global/L2. Measured r12: 146.7us, FETCH 74MB, WRITE 2.3MB, VGPR 128.
__global__ __launch_bounds__(512, 2) void conv23_k(
    const unsigned short* __restrict__ buf1, float* __restrict__ maxb,
    const unsigned short* __restrict__ Wall, const float* __restrict__ biasg) {

    __shared__ __align__(16) unsigned char ubuf[960 * 128];    // 122,880 B (union: xs | c2out)
    unsigned short* xs = (unsigned short*)ubuf;                // 24x40 px, 64 ci
    char* c2out = (char*)ubuf;                                 // 720 px * 128 B

    int z = blockIdx.z, br = z >> 3, odd = br & 1;
    int oy0 = blockIdx.y * 16, ox0 = blockIdx.x * 32;
    int t = threadIdx.x, lane = t & 63, wv = t >> 6;
    int n = lane & 31, kq = lane >> 5;

    const unsigned short* fb = buf1 + (size_t)z * (104 * 104 * 64);
    const short8* A2 = (const short8*)(Wall + (size_t)(8  + (br & 3)) * NWV);
    const short8* A3 = (const short8*)(Wall + (size_t)(12 + (br & 3)) * NWV);

    // ---- P1: stage xs FULL 64ci (24x40 px), 15 uint4/thread ----
    for (int e = t; e < 7680; e += 512) {
        int p = e >> 3, g = e & 7;
        int yy = p / 40, xx = p - yy * 40;
        uint4 v = *(const uint4*)(fb + ((size_t)((oy0 + yy) * 104 + ox0 + xx) << 6) + (g << 3));
        *(uint4*)(xs + (p << 6) + ((g ^ (xx & 7)) << 3)) = v;
    }

    // per-wave conv2-out pixel coords (3 chunks of 32, q-linear over 20x36, clamped)
    int q_[3], row2_[3], col2_[3];
#pragma unroll
    for (int jj = 0; jj < 3; jj++) {
        int q = 96 * wv + 32 * jj + n;
        q_[jj] = q;
        int qc = (q < 720) ? q : 719;
        int r2 = qc / 36;
        row2_[jj] = r2;
        col2_[jj] = qc - 36 * r2;
    }

    floatx16 acc2[3][2];   // [jj][cf]
#pragma unroll
    for (int jj = 0; jj < 3; jj++)
#pragma unroll
        for (int cf = 0; cf < 2; cf++)
#pragma unroll
            for (int i = 0; i < 16; i++) acc2[jj][cf][i] = 0.f;

    __syncthreads();   // xs staged

    // ---- conv2: single sweep over 4 ks quarters (full K resident in xs) ----
#pragma unroll
    for (int ks = 0; ks < 4; ks++) {
#pragma unroll
        for (int tb = 0; tb < 3; tb++) {
            short8 a[3][2];
#pragma unroll
            for (int ta = 0; ta < 3; ta++)
#pragma unroll
                for (int cf = 0; cf < 2; cf++)
                    a[ta][cf] = A2[(((ta * 3 + tb) * 4 + ks) * 2 + cf) * 64 + lane];
#pragma unroll
            for (int jj = 0; jj < 3; jj++) {
                int colx = col2_[jj] + 2 * tb;
                int gsw = ((ks * 2 + kq) ^ (colx & 7)) << 3;
#pragma unroll
                for (int ta = 0; ta < 3; ta++) {
                    int p = (row2_[jj] + 2 * ta) * 40 + colx;
                    short8 bfr = *(const short8*)(xs + (p << 6) + gsw);
                    acc2[jj][0] = __builtin_amdgcn_mfma_f32_32x32x16_bf16(a[ta][0], bfr, acc2[jj][0], 0, 0, 0);
                    acc2[jj][1] = __builtin_amdgcn_mfma_f32_32x32x16_bf16(a[ta][1], bfr, acc2[jj][1], 0, 0, 0);
                }
            }
        }
    }

    __syncthreads();   // xs reads complete before c2out (aliased) is written

    // ---- P3: conv2 epilogue -> c2out LDS (bias+relu, zero-mask even-parity borders) ----
    int rlo2 = (!odd && oy0 == 0)  ? 2  : 0;
    int rhi2 = (!odd && oy0 == 80) ? 18 : 20;
    int clo2 = (!odd && ox0 == 0)  ? 2  : 0;
    int chi2 = (!odd && ox0 == 64) ? 34 : 36;
    float4 bv2[2][4];
#pragma unroll
    for (int cf = 0; cf < 2; cf++)
#pragma unroll
        for (int rb = 0; rb < 4; rb++)
            bv2[cf][rb] = *(const float4*)(biasg + 64 + 32 * cf + 8 * rb + 4 * kq);

#pragma unroll
    for (int jj = 0; jj < 3; jj++) {
        if (q_[jj] < 720) {
            bool valid = (row2_[jj] >= rlo2) && (row2_[jj] < rhi2) &&
                         (col2_[jj] >= clo2) && (col2_[jj] < chi2);
            int key = col2_[jj] & 14;
#pragma unroll
            for (int cf = 0; cf < 2; cf++)
#pragma unroll
                for (int rb = 0; rb < 4; rb++) {
                    int u = kq + 2 * rb + 8 * cf;
                    float v0 = 0.f, v1 = 0.f, v2 = 0.f, v3 = 0.f;
                    if (valid) {
                        v0 = fmaxf(acc2[jj][cf][rb * 4 + 0] + bv2[cf][rb].x, 0.f);
                        v1 = fmaxf(acc2[jj][cf][rb * 4 + 1] + bv2[cf][rb].y, 0.f);
                        v2 = fmaxf(acc2[jj][cf][rb * 4 + 2] + bv2[cf][rb].z, 0.f);
                        v3 = fmaxf(acc2[jj][cf][rb * 4 + 3] + bv2[cf][rb].w, 0.f);
                    }
                    uint2 pk = make_uint2((unsigned)f2bf(v0) | ((unsigned)f2bf(v1) << 16),
                                          (unsigned)f2bf(v2) | ((unsigned)f2bf(v3) << 16));
                    *(uint2*)(c2out + q_[jj] * 128 + ((u ^ key) << 3)) = pk;
                }
        }
    }
    __syncthreads();

    // ---- P4: conv3 from c2out; wave owns out rows {2wv, 2wv+1} x 32 cols ----
    int r0 = 2 * wv;
    floatx16 acc3[2][2];   // [cf][pf]
#pragma unroll
    for (int cf = 0; cf < 2; cf++)
#pragma unroll
        for (int pf = 0; pf < 2; pf++)
#pragma unroll
            for (int i = 0; i < 16; i++) acc3[cf][pf][i] = 0.f;

#pragma unroll
    for (int ks = 0; ks < 4; ks++) {
#pragma unroll
        for (int tb = 0; tb < 3; tb++) {
            short8 a[3][2];
#pragma unroll
            for (int ta = 0; ta < 3; ta++)
#pragma unroll
                for (int cf = 0; cf < 2; cf++)
                    a[ta][cf] = A3[(((ta * 3 + tb) * 4 + ks) * 2 + cf) * 64 + lane];
            int col = n + 2 * tb;
            int key = col & 14;
            int ublk = 2 * (ks * 2 + kq);
            short8 bf[6];
#pragma unroll
            for (int rr = 0; rr < 6; rr++) {
                int q = (r0 + rr) * 36 + col;
                bf[rr] = *(const short8*)(c2out + q * 128 + ((ublk ^ key) << 3));
            }
#pragma unroll
            for (int ta = 0; ta < 3; ta++)
#pragma unroll
                for (int pf = 0; pf < 2; pf++) {
                    int rr = pf + 2 * ta;
                    acc3[0][pf] = __builtin_amdgcn_mfma_f32_32x32x16_bf16(a[ta][0], bf[rr], acc3[0][pf], 0, 0, 0);
                    acc3[1][pf] = __builtin_amdgcn_mfma_f32_32x32x16_bf16(a[ta][1], bf[rr], acc3[1][pf], 0, 0, 0);
                }
        }
    }

    // epilogue: bias + relu + max over 64 co -> maxb
    float4 bv3[2][4];
#pragma unroll
    for (int cf = 0; cf < 2; cf++)
#pragma unroll
        for (int rb = 0; rb < 4; rb++)
            bv3[cf][rb] = *(const float4*)(biasg + 128 + 32 * cf + 8 * rb + 4 * kq);

#pragma unroll
    for (int pf = 0; pf < 2; pf++) {
        float m = 0.f;
#pragma unroll
        for (int cf = 0; cf < 2; cf++)
#pragma unroll
            for (int rb = 0; rb < 4; rb++) {
                m = fmaxf(m, acc3[cf][pf][rb * 4 + 0] + bv3[cf][rb].x);
                m = fmaxf(m, acc3[cf][pf][rb * 4 + 1] + bv3[cf][rb].y);
                m = fmaxf(m, acc3[cf][pf][rb * 4 + 2] + bv3[cf][rb].z);
                m = fmaxf(m, acc3[cf][pf][rb * 4 + 3] + bv3[cf][rb].w);
            }
        m = fmaxf(m, 0.f);
        m = fmaxf(m, __shfl_xor(m, 32, 64));
        if (lane < 32)
            maxb[((size_t)z * 96 + oy0 + r0 + pf) * 96 + ox0 + n] = m;
    }
}

__global__ void final_k(const float* __restrict__ maxb, float* __restrict__ out) {
    int i = blockIdx.x * 256 + threadIdx.x;
    if (i < B * HW * HW) {
        int b = i / 9216, yx = i - b * 9216;
        float m = 0.f;
#pragma unroll
        for (int br = 0; br < 8; br++)
            m = fmaxf(m, maxb[((size_t)(br * 8 + b)) * 9216 + yx]);
        float v = 1.f / (1.f + expf(-m));
        out[i] = fminf(fmaxf(v, 1e-4f), 1.f - 1e-4f);
    }
}

// ---------------- launch ----------------

extern "C" void kernel_launch(void* const* d_in, const int* in_sizes, int n_in,
                              void* d_out, int out_size, void* d_ws, size_t ws_size,
                              hipStream_t stream) {
    const float* x     = (const float*)d_in[0];
    const float* dcn_w = (const float*)d_in[2];
    const float* dcn_b = (const float*)d_in[3];
    const float* c2w   = (const float*)d_in[4];
    const float* c2b   = (const float*)d_in[5];
    const float* c3w   = (const float*)d_in[6];
    const float* c3b   = (const float*)d_in[7];
    const float* gamma = (const float*)d_in[8];
    const float* beta  = (const float*)d_in[9];
    const float* mean  = (const float*)d_in[10];
    const float* var_  = (const float*)d_in[11];

    char* ws = (char*)d_ws;
    unsigned short* Wall = (unsigned short*)ws;                       // 1.18 MB
    size_t off = (size_t)16 * NWV * 2;
    float* biasg = (float*)(ws + off);            off += 1024;
    float* maxb  = (float*)(ws + off);            off += (size_t)64 * 9216 * 4;        // 2.36 MB
    unsigned short* xhwc = (unsigned short*)(ws + off); off += (size_t)B * 9216 * 64 * 2;    // 9.4 MB
    unsigned short* buf1 = (unsigned short*)(ws + off);                                 // 88.6 MB framed

    prep_all<<<4673, 256, 0, stream>>>(dcn_w, c2w, c3w, dcn_b, c2b, c3b,
                                       gamma, beta, mean, var_, x,
                                       Wall, biasg, xhwc, buf1);

    dim3 g1(4, 13, 64);
    conv1_k<<<g1, 256, 0, stream>>>(xhwc, buf1, Wall, biasg);

    dim3 g23(3, 6, 64);
    conv23_k<<<g23, 512, 0, stream>>>(buf1, maxb, Wall, biasg);

    final_k<<<(B * HW * HW + 255) / 256, 256, 0, stream>>>(maxb, (float*)d_out);
}

// Round 15
// 294.515 us; speedup vs baseline: 1.0388x; 1.0103x over previous
//
#include <hip/hip_runtime.h>
#include <math.h>

#define B 8
#define C 64
#define HW 96
#define NWV 36864            // per-variant weight elems: 9 taps * 64 co * 64 ci

typedef __attribute__((ext_vector_type(8)))  short short8;
typedef __attribute__((ext_vector_type(16))) float floatx16;

__device__ __forceinline__ unsigned short f2bf(float f) {
    unsigned int u = __float_as_uint(f);
    unsigned int r = (u + 0x7fffu + ((u >> 16) & 1u)) >> 16;
    return (unsigned short)r;
}

// tap rotation: effective kernel for rotation k is K'[i,j] = r^k(K)[i,j], r(K)[i,j]=K[2-j,i]
__device__ __forceinline__ void rotmap(int k, int ta, int tb, int& sa, int& sb) {
    switch (k) {
        case 0: sa = ta;     sb = tb;     break;
        case 1: sa = 2 - tb; sb = ta;     break;
        case 2: sa = 2 - ta; sb = 2 - tb; break;
        default: sa = tb;    sb = 2 - ta; break;
    }
}

// ---------------- fused prep: prep_w (blk 0..2303) + prep_x (2304..3071) +
// border_clear (3072..4671) + prep_bias (4672). All four are independent
// (disjoint outputs); branch is blockIdx-uniform so the prep_x barrier is safe.
__global__ __launch_bounds__(256) void prep_all(
    const float* __restrict__ dcn_w, const float* __restrict__ c2w,
    const float* __restrict__ c3w,
    const float* __restrict__ dcn_b, const float* __restrict__ c2b,
    const float* __restrict__ c3b,
    const float* __restrict__ gamma, const float* __restrict__ beta,
    const float* __restrict__ mean, const float* __restrict__ var_,
    const float* __restrict__ x,
    unsigned short* __restrict__ Wall, float* __restrict__ biasg,
    unsigned short* __restrict__ xhwc, unsigned short* __restrict__ buf1) {

    __shared__ float row[64 * 97];   // used only by the prep_x branch (24,832 B)
    int blk = blockIdx.x, t = threadIdx.x;

    if (blk < 2304) {
        // ---- prep_w ----
        int idx = blk * 256 + t;                 // 2304*256 == 16*NWV exactly
        int v = idx / NWV, rem = idx % NWV;
        int tap  = rem >> 12;
        int w12  = rem & 4095;
        int ks   = w12 >> 10;
        int cf   = (w12 >> 9) & 1;
        int lane = (w12 >> 3) & 63;
        int j    = w12 & 7;
        int co = cf * 32 + (lane & 31);
        int ci = ks * 16 + (lane >> 5) * 8 + j;
        int ta = tap / 3, tb = tap % 3;
        const float* src; int k, srcci, l;
        if (v < 8)       { k = v & 3;  srcci = (ci + 8 * v) & 63; src = dcn_w; l = 0; }
        else if (v < 12) { k = v - 8;  srcci = ci; src = c2w; l = 1; }
        else             { k = v - 12; srcci = ci; src = c3w; l = 2; }
        int sa, sb; rotmap(k, ta, tb, sa, sb);
        float s = gamma[l * 64 + co] * rsqrtf(var_[l * 64 + co] + 1e-5f);
        Wall[idx] = f2bf(src[((co * 64 + srcci) * 3 + sa) * 3 + sb] * s);
    } else if (blk < 3072) {
        // ---- prep_x: NCHW fp32 -> NHWC bf16 ----
        int by = blk - 2304;
        int b = by / 96, y = by % 96;
        for (int e = t; e < 6144; e += 256) {
            int c = e / 96, xx = e - c * 96;
            row[c * 97 + xx] = x[(((size_t)(b * 64 + c) * 96 + y) * 96) + xx];
        }
        __syncthreads();
        for (int e = t; e < 6144; e += 256) {
            int xx = e >> 6, c = e & 63;
            xhwc[(((size_t)(b * 96 + y) * 96 + xx) << 6) + c] = f2bf(row[c * 97 + xx]);
        }
    } else if (blk < 4672) {
        // ---- border_clear: zero 4-wide ring of even-branch 104x104 frames ----
        int l = blk - 3072;
        int bx = l % 50, idx = l / 50;           // bx 0..49, idx 0..31
        int br = (idx >> 3) * 2, b = idx & 7;
        int z = br * 8 + b;
        int i = bx * 32 + (t >> 3);              // 0..1599 border pixels
        int g = t & 7;
        int r, c;
        if (i < 416)      { r = i / 104;              c = i % 104; }
        else if (i < 832) { int j2 = i - 416; r = 100 + j2 / 104; c = j2 % 104; }
        else              { int j2 = i - 832; r = 4 + (j2 >> 3); int c8 = j2 & 7;
                            c = (c8 < 4) ? c8 : 92 + c8; }
        uint4 zero = make_uint4(0u, 0u, 0u, 0u);
        *(uint4*)(buf1 + (size_t)z * (104 * 104 * 64) + ((size_t)(r * 104 + c) << 6) + (g << 3)) = zero;
    } else {
        // ---- prep_bias ----
        if (t < 192) {
            int l = t >> 6, c = t & 63;
            const float* cb = (l == 0) ? dcn_b : ((l == 1) ? c2b : c3b);
            float s = gamma[l * 64 + c] * rsqrtf(var_[l * 64 + c] + 1e-5f);
            biasg[t] = cb[c] * s + beta[l * 64 + c] - mean[l * 64 + c] * s;
        }
    }
}

// ---------------- conv1 (r1 version): 1 branch/block -> framed buf1 (104x104, NHWC bf16) ----
__global__ __launch_bounds__(256, 2) void conv1_k(
    const unsigned short* __restrict__ xhwc, unsigned short* __restrict__ buf1,
    const unsigned short* __restrict__ Wall, const float* __restrict__ biasg) {

    __shared__ __align__(16) unsigned short xt[10 * 34 * 64];   // 43,520 B

    int z = blockIdx.z, br = z >> 3, b = z & 7, odd = br & 1;
    int fy0 = blockIdx.y * 8, fx0 = blockIdx.x * 32;
    int t = threadIdx.x, lane = t & 63, wv = t >> 6;
    int n = lane & 31, kq = lane >> 5;

    const unsigned short* xb = xhwc + ((size_t)b * 96 * 96 << 6);
    const short8* Ag = (const short8*)(Wall + (size_t)br * NWV);

    // stage x: tile rows fy0-5.. cols fx0-5.., zero OOB, key = tilecol&7
    for (int e = t; e < 2720; e += 256) {
        int p = e >> 3, g = e & 7;
        int yy = p / 34, xx = p - yy * 34;
        int gy = fy0 - 5 + yy, gx = fx0 - 5 + xx;
        uint4 v = make_uint4(0u, 0u, 0u, 0u);
        if ((unsigned)gy < 96u && (unsigned)gx < 96u)
            v = *(const uint4*)(xb + ((size_t)(gy * 96 + gx) << 6) + (g << 3));
        *(uint4*)(xt + (p << 6) + ((g ^ (xx & 7)) << 3)) = v;
    }
    __syncthreads();

    floatx16 acc[2][2];   // [cf][pf]
#pragma unroll
    for (int cf = 0; cf < 2; cf++)
#pragma unroll
        for (int pf = 0; pf < 2; pf++)
#pragma unroll
            for (int i = 0; i < 16; i++) acc[cf][pf][i] = 0.f;

#pragma unroll
    for (int ks = 0; ks < 4; ks++) {
#pragma unroll
        for (int tb = 0; tb < 3; tb++) {
            short8 a[3][2];
#pragma unroll
            for (int ta = 0; ta < 3; ta++)
#pragma unroll
                for (int cf = 0; cf < 2; cf++)
                    a[ta][cf] = Ag[(((ta * 3 + tb) * 4 + ks) * 2 + cf) * 64 + lane];
            int xx = n + tb;
            int g = ((ks * 2 + kq) ^ (xx & 7)) << 3;
            short8 bf[4];
#pragma unroll
            for (int rr = 0; rr < 4; rr++) {
                int p = (2 * wv + rr) * 34 + xx;
                bf[rr] = *(const short8*)(xt + (p << 6) + g);
            }
#pragma unroll
            for (int ta = 0; ta < 3; ta++)
#pragma unroll
                for (int pf = 0; pf < 2; pf++) {
                    int rr = pf + ta;
                    acc[0][pf] = __builtin_amdgcn_mfma_f32_32x32x16_bf16(a[ta][0], bf[rr], acc[0][pf], 0, 0, 0);
                    acc[1][pf] = __builtin_amdgcn_mfma_f32_32x32x16_bf16(a[ta][1], bf[rr], acc[1][pf], 0, 0, 0);
                }
        }
    }

    // bias (co0 = 4kq + 8rb + 32cf)
    float4 bv[2][4];
#pragma unroll
    for (int cf = 0; cf < 2; cf++)
#pragma unroll
        for (int rb = 0; rb < 4; rb++)
            bv[cf][rb] = *(const float4*)(biasg + 32 * cf + 8 * rb + 4 * kq);

    __syncthreads();   // xt reads done; reuse as transpose buffer (256 px * 128 B)
#pragma unroll
    for (int pf = 0; pf < 2; pf++) {
        int pq = (2 * wv + pf) * 32 + n;
        int key = (pq & 7) << 1;
#pragma unroll
        for (int cf = 0; cf < 2; cf++)
#pragma unroll
            for (int rb = 0; rb < 4; rb++) {
                int u = kq + 2 * rb + 8 * cf;
                float v0 = fmaxf(acc[cf][pf][rb * 4 + 0] + bv[cf][rb].x, 0.f);
                float v1 = fmaxf(acc[cf][pf][rb * 4 + 1] + bv[cf][rb].y, 0.f);
                float v2 = fmaxf(acc[cf][pf][rb * 4 + 2] + bv[cf][rb].z, 0.f);
                float v3 = fmaxf(acc[cf][pf][rb * 4 + 3] + bv[cf][rb].w, 0.f);
                uint2 pk = make_uint2((unsigned)f2bf(v0) | ((unsigned)f2bf(v1) << 16),
                                      (unsigned)f2bf(v2) | ((unsigned)f2bf(v3) << 16));
                *(uint2*)((char*)xt + pq * 128 + ((u ^ key) << 3)) = pk;
            }
    }
    __syncthreads();

    unsigned short* fb = buf1 + (size_t)z * (104 * 104 * 64);
    int lo = odd ? 0 : 4, hi = odd ? 104 : 100;
    for (int e = t; e < 2048; e += 256) {
        int px = e >> 3, g = e & 7;
        int key = (px & 7) << 1;
        uint4 v = *(const uint4*)((const char*)xt + px * 128 + (((2 * g) ^ key) << 3));
        int lr = px >> 5, nn = px & 31;
        int f = fy0 + lr, fc = fx0 + nn;
        if (f >= lo && f < hi && fc >= lo && fc < hi)
            *(uint4*)(fb + ((size_t)(f * 104 + fc) << 6) + (g << 3)) = v;
    }
}

// ---------------- fused conv2+conv3 -> maxbuf (r11/r12 version, verbatim: best measured) --
// Block: 512 thr (8 waves), 16x32 out tile. xs staged ONCE at full 64ci (122,880B);
// 3 barriers; c2out (720px x 128B) aliases xs after conv2 (guard barrier). Weights from
// global/L2. Measured r12/r14: 146-147us, FETCH 74MB, WRITE 2.3MB, VGPR 128.
__global__ __launch_bounds__(512, 2) void conv23_k(
    const unsigned short* __restrict__ buf1, float* __restrict__ maxb,
    const unsigned short* __restrict__ Wall, const float* __restrict__ biasg) {

    __shared__ __align__(16) unsigned char ubuf[960 * 128];    // 122,880 B (union: xs | c2out)
    unsigned short* xs = (unsigned short*)ubuf;                // 24x40 px, 64 ci
    char* c2out = (char*)ubuf;                                 // 720 px * 128 B

    int z = blockIdx.z, br = z >> 3, odd = br & 1;
    int oy0 = blockIdx.y * 16, ox0 = blockIdx.x * 32;
    int t = threadIdx.x, lane = t & 63, wv = t >> 6;
    int n = lane & 31, kq = lane >> 5;

    const unsigned short* fb = buf1 + (size_t)z * (104 * 104 * 64);
    const short8* A2 = (const short8*)(Wall + (size_t)(8  + (br & 3)) * NWV);
    const short8* A3 = (const short8*)(Wall + (size_t)(12 + (br & 3)) * NWV);

    // ---- P1: stage xs FULL 64ci (24x40 px), 15 uint4/thread ----
    for (int e = t; e < 7680; e += 512) {
        int p = e >> 3, g = e & 7;
        int yy = p / 40, xx = p - yy * 40;
        uint4 v = *(const uint4*)(fb + ((size_t)((oy0 + yy) * 104 + ox0 + xx) << 6) + (g << 3));
        *(uint4*)(xs + (p << 6) + ((g ^ (xx & 7)) << 3)) = v;
    }

    // per-wave conv2-out pixel coords (3 chunks of 32, q-linear over 20x36, clamped)
    int q_[3], row2_[3], col2_[3];
#pragma unroll
    for (int jj = 0; jj < 3; jj++) {
        int q = 96 * wv + 32 * jj + n;
        q_[jj] = q;
        int qc = (q < 720) ? q : 719;
        int r2 = qc / 36;
        row2_[jj] = r2;
        col2_[jj] = qc - 36 * r2;
    }

    floatx16 acc2[3][2];   // [jj][cf]
#pragma unroll
    for (int jj = 0; jj < 3; jj++)
#pragma unroll
        for (int cf = 0; cf < 2; cf++)
#pragma unroll
            for (int i = 0; i < 16; i++) acc2[jj][cf][i] = 0.f;

    __syncthreads();   // xs staged

    // ---- conv2: single sweep over 4 ks quarters (full K resident in xs) ----
#pragma unroll
    for (int ks = 0; ks < 4; ks++) {
#pragma unroll
        for (int tb = 0; tb < 3; tb++) {
            short8 a[3][2];
#pragma unroll
            for (int ta = 0; ta < 3; ta++)
#pragma unroll
                for (int cf = 0; cf < 2; cf++)
                    a[ta][cf] = A2[(((ta * 3 + tb) * 4 + ks) * 2 + cf) * 64 + lane];
#pragma unroll
            for (int jj = 0; jj < 3; jj++) {
                int colx = col2_[jj] + 2 * tb;
                int gsw = ((ks * 2 + kq) ^ (colx & 7)) << 3;
#pragma unroll
                for (int ta = 0; ta < 3; ta++) {
                    int p = (row2_[jj] + 2 * ta) * 40 + colx;
                    short8 bfr = *(const short8*)(xs + (p << 6) + gsw);
                    acc2[jj][0] = __builtin_amdgcn_mfma_f32_32x32x16_bf16(a[ta][0], bfr, acc2[jj][0], 0, 0, 0);
                    acc2[jj][1] = __builtin_amdgcn_mfma_f32_32x32x16_bf16(a[ta][1], bfr, acc2[jj][1], 0, 0, 0);
                }
            }
        }
    }

    __syncthreads();   // xs reads complete before c2out (aliased) is written

    // ---- P3: conv2 epilogue -> c2out LDS (bias+relu, zero-mask even-parity borders) ----
    int rlo2 = (!odd && oy0 == 0)  ? 2  : 0;
    int rhi2 = (!odd && oy0 == 80) ? 18 : 20;
    int clo2 = (!odd && ox0 == 0)  ? 2  : 0;
    int chi2 = (!odd && ox0 == 64) ? 34 : 36;
    float4 bv2[2][4];
#pragma unroll
    for (int cf = 0; cf < 2; cf++)
#pragma unroll
        for (int rb = 0; rb < 4; rb++)
            bv2[cf][rb] = *(const float4*)(biasg + 64 + 32 * cf + 8 * rb + 4 * kq);

#pragma unroll
    for (int jj = 0; jj < 3; jj++) {
        if (q_[jj] < 720) {
            bool valid = (row2_[jj] >= rlo2) && (row2_[jj] < rhi2) &&
                         (col2_[jj] >= clo2) && (col2_[jj] < chi2);
            int key = col2_[jj] & 14;
#pragma unroll
            for (int cf = 0; cf < 2; cf++)
#pragma unroll
                for (int rb = 0; rb < 4; rb++) {
                    int u = kq + 2 * rb + 8 * cf;
                    float v0 = 0.f, v1 = 0.f, v2 = 0.f, v3 = 0.f;
                    if (valid) {
                        v0 = fmaxf(acc2[jj][cf][rb * 4 + 0] + bv2[cf][rb].x, 0.f);
                        v1 = fmaxf(acc2[jj][cf][rb * 4 + 1] + bv2[cf][rb].y, 0.f);
                        v2 = fmaxf(acc2[jj][cf][rb * 4 + 2] + bv2[cf][rb].z, 0.f);
                        v3 = fmaxf(acc2[jj][cf][rb * 4 + 3] + bv2[cf][rb].w, 0.f);
                    }
                    uint2 pk = make_uint2((unsigned)f2bf(v0) | ((unsigned)f2bf(v1) << 16),
                                          (unsigned)f2bf(v2) | ((unsigned)f2bf(v3) << 16));
                    *(uint2*)(c2out + q_[jj] * 128 + ((u ^ key) << 3)) = pk;
                }
        }
    }
    __syncthreads();

    // ---- P4: conv3 from c2out; wave owns out rows {2wv, 2wv+1} x 32 cols ----
    int r0 = 2 * wv;
    floatx16 acc3[2][2];   // [cf][pf]
#pragma unroll
    for (int cf = 0; cf < 2; cf++)
#pragma unroll
        for (int pf = 0; pf < 2; pf++)
#pragma unroll
            for (int i = 0; i < 16; i++) acc3[cf][pf][i] = 0.f;

#pragma unroll
    for (int ks = 0; ks < 4; ks++) {
#pragma unroll
        for (int tb = 0; tb < 3; tb++) {
            short8 a[3][2];
#pragma unroll
            for (int ta = 0; ta < 3; ta++)
#pragma unroll
                for (int cf = 0; cf < 2; cf++)
                    a[ta][cf] = A3[(((ta * 3 + tb) * 4 + ks) * 2 + cf) * 64 + lane];
            int col = n + 2 * tb;
            int key = col & 14;
            int ublk = 2 * (ks * 2 + kq);
            short8 bf[6];
#pragma unroll
            for (int rr = 0; rr < 6; rr++) {
                int q = (r0 + rr) * 36 + col;
                bf[rr] = *(const short8*)(c2out + q * 128 + ((ublk ^ key) << 3));
            }
#pragma unroll
            for (int ta = 0; ta < 3; ta++)
#pragma unroll
                for (int pf = 0; pf < 2; pf++) {
                    int rr = pf + 2 * ta;
                    acc3[0][pf] = __builtin_amdgcn_mfma_f32_32x32x16_bf16(a[ta][0], bf[rr], acc3[0][pf], 0, 0, 0);
                    acc3[1][pf] = __builtin_amdgcn_mfma_f32_32x32x16_bf16(a[ta][1], bf[rr], acc3[1][pf], 0, 0, 0);
                }
        }
    }

    // epilogue: bias + relu + max over 64 co -> maxb
    float4 bv3[2][4];
#pragma unroll
    for (int cf = 0; cf < 2; cf++)
#pragma unroll
        for (int rb = 0; rb < 4; rb++)
            bv3[cf][rb] = *(const float4*)(biasg + 128 + 32 * cf + 8 * rb + 4 * kq);

#pragma unroll
    for (int pf = 0; pf < 2; pf++) {
        float m = 0.f;
#pragma unroll
        for (int cf = 0; cf < 2; cf++)
#pragma unroll
            for (int rb = 0; rb < 4; rb++) {
                m = fmaxf(m, acc3[cf][pf][rb * 4 + 0] + bv3[cf][rb].x);
                m = fmaxf(m, acc3[cf][pf][rb * 4 + 1] + bv3[cf][rb].y);
                m = fmaxf(m, acc3[cf][pf][rb * 4 + 2] + bv3[cf][rb].z);
                m = fmaxf(m, acc3[cf][pf][rb * 4 + 3] + bv3[cf][rb].w);
            }
        m = fmaxf(m, 0.f);
        m = fmaxf(m, __shfl_xor(m, 32, 64));
        if (lane < 32)
            maxb[((size_t)z * 96 + oy0 + r0 + pf) * 96 + ox0 + n] = m;
    }
}

__global__ void final_k(const float* __restrict__ maxb, float* __restrict__ out) {
    int i = blockIdx.x * 256 + threadIdx.x;
    if (i < B * HW * HW) {
        int b = i / 9216, yx = i - b * 9216;
        float m = 0.f;
#pragma unroll
        for (int br = 0; br < 8; br++)
            m = fmaxf(m, maxb[((size_t)(br * 8 + b)) * 9216 + yx]);
        float v = 1.f / (1.f + expf(-m));
        out[i] = fminf(fmaxf(v, 1e-4f), 1.f - 1e-4f);
    }
}

// ---------------- launch ----------------

extern "C" void kernel_launch(void* const* d_in, const int* in_sizes, int n_in,
                              void* d_out, int out_size, void* d_ws, size_t ws_size,
                              hipStream_t stream) {
    const float* x     = (const float*)d_in[0];
    const float* dcn_w = (const float*)d_in[2];
    const float* dcn_b = (const float*)d_in[3];
    const float* c2w   = (const float*)d_in[4];
    const float* c2b   = (const float*)d_in[5];
    const float* c3w   = (const float*)d_in[6];
    const float* c3b   = (const float*)d_in[7];
    const float* gamma = (const float*)d_in[8];
    const float* beta  = (const float*)d_in[9];
    const float* mean  = (const float*)d_in[10];
    const float* var_  = (const float*)d_in[11];

    char* ws = (char*)d_ws;
    unsigned short* Wall = (unsigned short*)ws;                       // 1.18 MB
    size_t off = (size_t)16 * NWV * 2;
    float* biasg = (float*)(ws + off);            off += 1024;
    float* maxb  = (float*)(ws + off);            off += (size_t)64 * 9216 * 4;        // 2.36 MB
    unsigned short* xhwc = (unsigned short*)(ws + off); off += (size_t)B * 9216 * 64 * 2;    // 9.4 MB
    unsigned short* buf1 = (unsigned short*)(ws + off);                                 // 88.6 MB framed

    prep_all<<<4673, 256, 0, stream>>>(dcn_w, c2w, c3w, dcn_b, c2b, c3b,
                                       gamma, beta, mean, var_, x,
                                       Wall, biasg, xhwc, buf1);

    dim3 g1(4, 13, 64);
    conv1_k<<<g1, 256, 0, stream>>>(xhwc, buf1, Wall, biasg);

    dim3 g23(3, 6, 64);
    conv23_k<<<g23, 512, 0, stream>>>(buf1, maxb, Wall, biasg);

    final_k<<<(B * HW * HW + 255) / 256, 256, 0, stream>>>(maxb, (float*)d_out);
}